// Round 8
// baseline (206.534 us; speedup 1.0000x reference)
//
#include <hip/hip_runtime.h>
#include <stdint.h>

// SeqAttnMatch: B=32, LP=2048, LQ=512, D=256, fp32 in/out. Single-plane fp16 pipeline.
// k_attn: 64 rows/block, 8 waves, 2 blocks/CU (4 waves/SIMD), fused x-proj.
#define B_  32
#define LP_ 2048
#define LQ_ 512
#define D_  256

typedef __attribute__((ext_vector_type(8))) short short8;      // 8 x 16-bit
typedef __attribute__((ext_vector_type(8))) _Float16 f16x8;    // MFMA A/B frag (4 VGPRs)
typedef __attribute__((ext_vector_type(4))) float f32x4;

__device__ __forceinline__ ushort f2h(float x) {
    union { _Float16 h; ushort u; } v;
    v.h = (_Float16)x;                 // RNE convert
    return v.u;
}
// async global->LDS, 16B/lane; HW writes lds_base + lane*16 (wave-uniform base).
__device__ __forceinline__ void gl_lds16(const void* g, void* l) {
    __builtin_amdgcn_global_load_lds(
        (const __attribute__((address_space(1))) void*)g,
        (__attribute__((address_space(3))) void*)l, 16, 0, 0);
}

// Fragment-blocked layout: 1KB blocks of 512 ushorts. Element for lane
// L=quad*16+c, position L*8 + j, holds M[row_tile*16 + c][k0 + quad*8 + j].

// ---- K0: fused W f32->f16 frag convert (blocks 0..255) + y transpose (256..767) ----
__global__ void k_prep(const float* __restrict__ W, const float* __restrict__ y,
                       ushort* __restrict__ Whf, ushort* __restrict__ yf) {
    __shared__ float t[32 * 260];
    if (blockIdx.x < 256) {
        int i = blockIdx.x * 256 + threadIdx.x;
        int e = i >> 8, k = i & 255;
        size_t off = (size_t)((k >> 5) * 16 + (e >> 4)) * 512 +
                     ((k >> 3) & 3) * 128 + (e & 15) * 8 + (k & 7);
        Whf[off] = f2h(W[i]);
        return;
    }
    int bid = blockIdx.x - 256;      // 512 blocks
    int b = bid >> 4, qc = bid & 15;
    int tid = threadIdx.x;
    int ql = tid >> 3;               // 0..31
    int d0 = (tid & 7) * 4;
#pragma unroll
    for (int p = 0; p < 8; p++) {
        int d = p * 32 + d0;
        float4 v = *(const float4*)(y + ((size_t)(b * LQ_ + qc * 32 + ql) * 256 + d));
        t[ql * 260 + d + 0] = v.x; t[ql * 260 + d + 1] = v.y;
        t[ql * 260 + d + 2] = v.z; t[ql * 260 + d + 3] = v.w;
    }
    __syncthreads();
    int w = tid >> 6, L = tid & 63, c = L & 15, quad = L >> 4;
#pragma unroll
    for (int ii = 0; ii < 4; ii++) {
        int nt = w * 4 + ii;
        short8 o;
#pragma unroll
        for (int j = 0; j < 8; j++)
            o[j] = (short)f2h(t[(quad * 8 + j) * 260 + nt * 16 + c]);
        *(short8*)(yf + ((size_t)(b * 256 + qc * 16 + nt) * 512 + L * 8)) = o;
    }
}

// ---- K1: y-proj = relu(y @ W^T + b) -> frag-blocked f16 (256 blocks, 64 rows each) ----
__global__ __launch_bounds__(256, 3) void k_proj(const float* __restrict__ y,
                                                 const ushort* __restrict__ Whf,
                                                 const float* __restrict__ bias,
                                                 ushort* __restrict__ Oy) {
    __shared__ __align__(16) ushort Ws[16704];   // 32KB ping-pong, then 33.3KB transpose
    const int tid  = threadIdx.x;
    const int w    = tid >> 6;
    const int L    = tid & 63;
    const int c    = L & 15;
    const int quad = L >> 4;
    const int row0 = blockIdx.x * 64 + w * 16;
    const int arow = row0 + c;

    f32x4 acc[16];
#pragma unroll
    for (int i = 0; i < 16; i++) acc[i] = (f32x4)0.f;

#define PSTAGE(kc, p)                                                          \
    {                                                                          \
        _Pragma("unroll")                                                      \
        for (int ii = 0; ii < 4; ii++) {                                       \
            int i = w * 4 + ii;                                                \
            gl_lds16(Whf + (size_t)(kc) * 8192 + i * 512 + L * 8,              \
                     (char*)Ws + (p) * 16384 + i * 1024);                      \
        }                                                                      \
    }

    PSTAGE(0, 0);
    float4 nx0 = *(const float4*)(y + (size_t)arow * 256 + quad * 8);
    float4 nx1 = *(const float4*)(y + (size_t)arow * 256 + quad * 8 + 4);

    for (int kc = 0; kc < 8; kc++) {
        __syncthreads();
        if (kc < 7) PSTAGE(kc + 1, (kc + 1) & 1);
        float4 cx0 = nx0, cx1 = nx1;
        if (kc < 7) {
            nx0 = *(const float4*)(y + (size_t)arow * 256 + (kc + 1) * 32 + quad * 8);
            nx1 = *(const float4*)(y + (size_t)arow * 256 + (kc + 1) * 32 + quad * 8 + 4);
        }
        float xs[8] = {cx0.x, cx0.y, cx0.z, cx0.w, cx1.x, cx1.y, cx1.z, cx1.w};
        f16x8 ah;
#pragma unroll
        for (int j = 0; j < 8; j++) ah[j] = (_Float16)xs[j];
        const ushort* buf = Ws + (kc & 1) * 8192;
#pragma unroll
        for (int nt = 0; nt < 16; nt++) {
            f16x8 bh = *(const f16x8*)(buf + nt * 512 + L * 8);
            acc[nt] = __builtin_amdgcn_mfma_f32_16x16x32_f16(ah, bh, acc[nt], 0, 0, 0);
        }
    }

    // epilogue: bias+relu, per-wave LDS transpose C-layout -> B-frag layout
    __syncthreads();                 // all waves done reading Ws
    float* tr = (float*)Ws + w * (16 * 130);
    const int rt_g = row0 >> 4;
#pragma unroll
    for (int half = 0; half < 2; half++) {
#pragma unroll
        for (int nt8 = 0; nt8 < 8; nt8++) {
            int nt = half * 8 + nt8;
            float bv = bias[nt * 16 + c];
#pragma unroll
            for (int r = 0; r < 4; r++)
                tr[(quad * 4 + r) * 130 + nt8 * 16 + c] = fmaxf(acc[nt][r] + bv, 0.f);
        }
#pragma unroll
        for (int ec4 = 0; ec4 < 4; ec4++) {
            int ec = half * 4 + ec4;
            short8 hh;
#pragma unroll
            for (int j = 0; j < 8; j++)
                hh[j] = (short)f2h(tr[c * 130 + ec4 * 32 + quad * 8 + j]);
            size_t blk = (size_t)(rt_g >> 5) * 256 + ec * 32 + (rt_g & 31);
            *(short8*)(Oy + blk * 512 + L * 8) = hh;
        }
    }
}

// ---- K2: fused x-proj + scores + softmax + match. 64 rows/block, 1024 blocks, ----
// 8 waves, 64KB LDS, 2 blocks/CU (4 waves/SIMD). Wave = (rh=w>>2, qh=w&3).
// LDS: x-frags [0,32K) units rsg*8+kc; pfrag [32K,64K); alpha reuses all 64KB.
__global__ __launch_bounds__(512, 4) void k_attn(const float* __restrict__ x,
                                                 const ushort* __restrict__ Whf,
                                                 const float* __restrict__ bias,
                                                 const ushort* __restrict__ ypf,
                                                 const ushort* __restrict__ yf,
                                                 float* __restrict__ out) {
    __shared__ __align__(16) ushort lds[32768];   // 64KB
    const int tid  = threadIdx.x;
    const int w    = tid >> 6;       // 0..7
    const int L    = tid & 63;
    const int c    = L & 15;
    const int quad = L >> 4;
    const int rh   = w >> 2;         // row-half (rows rh*32..rh*32+31)
    const int qh   = w & 3;          // q-quarter (A/B) and d-quarter (C)

    // XCD-affinity swizzle: XCD x sees only batches 4x..4x+3
    const int bid = blockIdx.x;      // 1024
    const int jj  = bid >> 3;        // 0..127
    const int b   = (bid & 7) * 4 + (jj >> 5);
    const int mt  = jj & 31;         // 0..31, 64 rows each
    const int m0  = mt * 64;

    // ---- stage x A-frags (inline f32->f16): 32 units (rsg*8+kc) x 1KB ----
#pragma unroll
    for (int ii = 0; ii < 4; ii++) {
        int unit = w * 4 + ii;
        int rsg = unit >> 3, kc = unit & 7;
        const float* xs = x + ((size_t)(b * LP_ + m0 + rsg * 16 + c)) * 256 + kc * 32 + quad * 8;
        float4 v0 = *(const float4*)xs;
        float4 v1 = *(const float4*)(xs + 4);
        f16x8 h;
        h[0] = (_Float16)v0.x; h[1] = (_Float16)v0.y;
        h[2] = (_Float16)v0.z; h[3] = (_Float16)v0.w;
        h[4] = (_Float16)v1.x; h[5] = (_Float16)v1.y;
        h[6] = (_Float16)v1.z; h[7] = (_Float16)v1.w;
        *(f16x8*)(lds + unit * 512 + L * 8) = h;
    }
    __syncthreads();                 // x-frags visible

    // ---- x-proj: wave w = e-eighth (2 nt), ALL 4 row-tiles ----
    {
        float bv[2];
#pragma unroll
        for (int ne = 0; ne < 2; ne++) bv[ne] = bias[(w * 2 + ne) * 16 + c];
        f32x4 pacc[4][2];
#pragma unroll
        for (int rsg = 0; rsg < 4; rsg++)
#pragma unroll
            for (int ne = 0; ne < 2; ne++) pacc[rsg][ne] = (f32x4)0.f;
        for (int kc = 0; kc < 8; kc++) {
            f16x8 wb[2];
#pragma unroll
            for (int ne = 0; ne < 2; ne++)
                wb[ne] = *(const f16x8*)(Whf + ((size_t)(kc * 16 + w * 2 + ne)) * 512 + L * 8);
#pragma unroll
            for (int rsg = 0; rsg < 4; rsg++) {
                f16x8 ah = *(const f16x8*)(lds + (rsg * 8 + kc) * 512 + L * 8);
                pacc[rsg][0] = __builtin_amdgcn_mfma_f32_16x16x32_f16(ah, wb[0], pacc[rsg][0], 0, 0, 0);
                pacc[rsg][1] = __builtin_amdgcn_mfma_f32_16x16x32_f16(ah, wb[1], pacc[rsg][1], 0, 0, 0);
            }
        }
        // scatter relu(acc+bias) f16 -> pfrag LDS [32K,64K) in A-frag layout.
        // e = (w*2+ne)*16+c -> unit kc' = (w*2+ne)>>1 = w; quad' = ne*2+(c>>3); j = c&7.
#pragma unroll
        for (int rsg = 0; rsg < 4; rsg++)
#pragma unroll
            for (int ne = 0; ne < 2; ne++) {
#pragma unroll
                for (int r = 0; r < 4; r++) {
                    float v = fmaxf(pacc[rsg][ne][r] + bv[ne], 0.f);
                    int off = 16384 + (rsg * 8 + w) * 512 +
                              (ne * 2 + (c >> 3)) * 128 + (quad * 4 + r) * 8 + (c & 7);
                    lds[off] = f2h(v);
                }
            }
    }

    f32x4 sc[2][8];
#pragma unroll
    for (int rs = 0; rs < 2; rs++)
#pragma unroll
        for (int qt = 0; qt < 8; qt++) sc[rs][qt] = (f32x4)0.f;
    __syncthreads();                 // pfrag visible

    // ---- Phase A: barrier-free; wave (rh,qh): row-tiles 2rh,2rh+1, qt qh*8.. ----
    const ushort* pf = lds + 16384;  // proj A-frags
    const ushort* yb = ypf + (size_t)b * 256 * 512;
    for (int kc = 0; kc < 8; kc++) {
        f16x8 ah0 = *(const f16x8*)(pf + ((2 * rh) * 8 + kc) * 512 + L * 8);
        f16x8 ah1 = *(const f16x8*)(pf + ((2 * rh + 1) * 8 + kc) * 512 + L * 8);
#pragma unroll
        for (int qt = 0; qt < 8; qt++) {
            f16x8 bh = *(const f16x8*)(yb + ((size_t)kc * 32 + qh * 8 + qt) * 512 + L * 8);
            sc[0][qt] = __builtin_amdgcn_mfma_f32_16x16x32_f16(ah0, bh, sc[0][qt], 0, 0, 0);
            sc[1][qt] = __builtin_amdgcn_mfma_f32_16x16x32_f16(ah1, bh, sc[1][qt], 0, 0, 0);
        }
    }

    // ---- Phase B: softmax; wave holds q-quarter qh of rows rh*32..+31 ----
    __syncthreads();                 // pfrag/x-frag reads done; lds reusable
    float* red  = (float*)lds;       // [64][4] partial max
    float* red2 = red + 256;         // [64][4] partial sum
    float inv[2][4];
#pragma unroll
    for (int rs = 0; rs < 2; rs++)
#pragma unroll
        for (int r = 0; r < 4; r++) {
            float pm = sc[rs][0][r];
#pragma unroll
            for (int qt = 1; qt < 8; qt++) pm = fmaxf(pm, sc[rs][qt][r]);
#pragma unroll
            for (int mask = 1; mask <= 8; mask <<= 1) pm = fmaxf(pm, __shfl_xor(pm, mask));
            if (c == 0) red[(rh * 32 + rs * 16 + quad * 4 + r) * 4 + qh] = pm;
        }
    __syncthreads();
#pragma unroll
    for (int rs = 0; rs < 2; rs++)
#pragma unroll
        for (int r = 0; r < 4; r++) {
            int row = rh * 32 + rs * 16 + quad * 4 + r;
            float m = fmaxf(fmaxf(red[row * 4], red[row * 4 + 1]),
                            fmaxf(red[row * 4 + 2], red[row * 4 + 3]));
            float ps = 0.f;
#pragma unroll
            for (int qt = 0; qt < 8; qt++) {
                float e = __expf(sc[rs][qt][r] - m);
                sc[rs][qt][r] = e;
                ps += e;
            }
#pragma unroll
            for (int mask = 1; mask <= 8; mask <<= 1) ps += __shfl_xor(ps, mask);
            if (c == 0) red2[row * 4 + qh] = ps;
        }
    __syncthreads();
#pragma unroll
    for (int rs = 0; rs < 2; rs++)
#pragma unroll
        for (int r = 0; r < 4; r++) {
            int row = rh * 32 + rs * 16 + quad * 4 + r;
            inv[rs][r] = 1.f / (red2[row * 4] + red2[row * 4 + 1] +
                                red2[row * 4 + 2] + red2[row * 4 + 3]);
        }
    __syncthreads();                 // red/red2 reads done before alpha overwrites

    // alpha (f16) -> LDS [64 rows][512 q], xor-swizzled 8-elem chunks (full 64KB)
#pragma unroll
    for (int rs = 0; rs < 2; rs++)
#pragma unroll
        for (int r = 0; r < 4; r++) {
            int m_loc = rh * 32 + rs * 16 + quad * 4 + r;
            int swz = m_loc & 7;
            float iv = inv[rs][r];
#pragma unroll
            for (int qt = 0; qt < 8; qt++) {
                int q = qh * 128 + qt * 16 + c;
                lds[m_loc * 512 + (((q >> 3) ^ swz) << 3) + (c & 7)] = f2h(sc[rs][qt][r] * iv);
            }
        }
    __syncthreads();

    // ---- Phase C: out = alpha(LDS) @ yf(global). wave (rh, dh=qh), full q sweep. ----
    f32x4 o[2][4];
#pragma unroll
    for (int rs = 0; rs < 2; rs++)
#pragma unroll
        for (int dt = 0; dt < 4; dt++) o[rs][dt] = (f32x4)0.f;
    const int swzA = c & 7;          // ((rh*2+rs)*16+c)&7 == c&7
    for (int kcq = 0; kcq < 16; kcq++) {
        int chunk = kcq * 4 + quad;
        f16x8 af0 = *(const f16x8*)(lds + ((rh * 2) * 16 + c) * 512 + ((chunk ^ swzA) << 3));
        f16x8 af1 = *(const f16x8*)(lds + ((rh * 2 + 1) * 16 + c) * 512 + ((chunk ^ swzA) << 3));
        const ushort* ybf = yf + ((size_t)(b * 256 + kcq * 16 + qh * 4)) * 512;
#pragma unroll
        for (int dt = 0; dt < 4; dt++) {
            f16x8 bfr = *(const f16x8*)(ybf + dt * 512 + L * 8);
            o[0][dt] = __builtin_amdgcn_mfma_f32_16x16x32_f16(af0, bfr, o[0][dt], 0, 0, 0);
            o[1][dt] = __builtin_amdgcn_mfma_f32_16x16x32_f16(af1, bfr, o[1][dt], 0, 0, 0);
        }
    }

    // ---- direct store (each wave owns rows rh-half x d-quarter qh) ----
#pragma unroll
    for (int rs = 0; rs < 2; rs++)
#pragma unroll
        for (int dt = 0; dt < 4; dt++)
#pragma unroll
            for (int r = 0; r < 4; r++) {
                int row = (rh * 2 + rs) * 16 + quad * 4 + r;
                out[(size_t)(b * LP_ + m0 + row) * 256 + qh * 64 + dt * 16 + c] =
                    o[rs][dt][r];
            }
}

extern "C" void kernel_launch(void* const* d_in, const int* in_sizes, int n_in,
                              void* d_out, int out_size, void* d_ws, size_t ws_size,
                              hipStream_t stream) {
    const float* x    = (const float*)d_in[0];
    const float* y    = (const float*)d_in[1];
    const float* W    = (const float*)d_in[2];
    const float* bias = (const float*)d_in[3];
    float* out = (float*)d_out;

    char* ws = (char*)d_ws;
    size_t off = 0;
    ushort* Whf = (ushort*)(ws + off); off += (size_t)D_ * D_ * 2;          // 128KB
    ushort* yfb = (ushort*)(ws + off); off += (size_t)B_ * D_ * LQ_ * 2;    // 8MB
    ushort* ypf = (ushort*)(ws + off); off += (size_t)B_ * LQ_ * D_ * 2;    // 8MB

    k_prep<<<768, 256, 0, stream>>>(W, y, Whf, yfb);
    k_proj<<<256, 256, 0, stream>>>(y, Whf, bias, ypf);
    k_attn<<<B_ * 32, 512, 0, stream>>>(x, Whf, bias, ypf, yfb, out);
}

// Round 9
// 206.413 us; speedup vs baseline: 1.0006x; 1.0006x over previous
//
#include <hip/hip_runtime.h>
#include <stdint.h>

// SeqAttnMatch: B=32, LP=2048, LQ=512, D=256, fp32 in/out. Single-plane fp16 pipeline.
// k_attn: fused x-proj + scores + softmax + match; DMA-staged Whf (proj) and ypf
// (Phase A) with ping-pong LDS (m97 pattern). 32 rows/block, 4 waves, 48KB LDS.
#define B_  32
#define LP_ 2048
#define LQ_ 512
#define D_  256

typedef __attribute__((ext_vector_type(8))) short short8;      // 8 x 16-bit
typedef __attribute__((ext_vector_type(8))) _Float16 f16x8;    // MFMA A/B frag (4 VGPRs)
typedef __attribute__((ext_vector_type(4))) float f32x4;

__device__ __forceinline__ ushort f2h(float x) {
    union { _Float16 h; ushort u; } v;
    v.h = (_Float16)x;                 // RNE convert
    return v.u;
}
// async global->LDS, 16B/lane; HW writes lds_base + lane*16 (wave-uniform base).
__device__ __forceinline__ void gl_lds16(const void* g, void* l) {
    __builtin_amdgcn_global_load_lds(
        (const __attribute__((address_space(1))) void*)g,
        (__attribute__((address_space(3))) void*)l, 16, 0, 0);
}

// Fragment-blocked layout: 1KB blocks of 512 ushorts. Element for lane
// L=quad*16+c, position L*8 + j, holds M[row_tile*16 + c][k0 + quad*8 + j].

// ---- K0: fused W f32->f16 frag convert (blocks 0..255) + y transpose (256..767) ----
__global__ void k_prep(const float* __restrict__ W, const float* __restrict__ y,
                       ushort* __restrict__ Whf, ushort* __restrict__ yf) {
    __shared__ float t[32 * 260];
    if (blockIdx.x < 256) {
        int i = blockIdx.x * 256 + threadIdx.x;
        int e = i >> 8, k = i & 255;
        size_t off = (size_t)((k >> 5) * 16 + (e >> 4)) * 512 +
                     ((k >> 3) & 3) * 128 + (e & 15) * 8 + (k & 7);
        Whf[off] = f2h(W[i]);
        return;
    }
    int bid = blockIdx.x - 256;      // 512 blocks
    int b = bid >> 4, qc = bid & 15;
    int tid = threadIdx.x;
    int ql = tid >> 3;               // 0..31
    int d0 = (tid & 7) * 4;
#pragma unroll
    for (int p = 0; p < 8; p++) {
        int d = p * 32 + d0;
        float4 v = *(const float4*)(y + ((size_t)(b * LQ_ + qc * 32 + ql) * 256 + d));
        t[ql * 260 + d + 0] = v.x; t[ql * 260 + d + 1] = v.y;
        t[ql * 260 + d + 2] = v.z; t[ql * 260 + d + 3] = v.w;
    }
    __syncthreads();
    int w = tid >> 6, L = tid & 63, c = L & 15, quad = L >> 4;
#pragma unroll
    for (int ii = 0; ii < 4; ii++) {
        int nt = w * 4 + ii;
        short8 o;
#pragma unroll
        for (int j = 0; j < 8; j++)
            o[j] = (short)f2h(t[(quad * 8 + j) * 260 + nt * 16 + c]);
        *(short8*)(yf + ((size_t)(b * 256 + qc * 16 + nt) * 512 + L * 8)) = o;
    }
}

// ---- K1: y-proj = relu(y @ W^T + b) -> frag-blocked f16 (256 blocks, 64 rows each) ----
__global__ __launch_bounds__(256, 3) void k_proj(const float* __restrict__ y,
                                                 const ushort* __restrict__ Whf,
                                                 const float* __restrict__ bias,
                                                 ushort* __restrict__ Oy) {
    __shared__ __align__(16) ushort Ws[16704];   // 32KB ping-pong, then 33.3KB transpose
    const int tid  = threadIdx.x;
    const int w    = tid >> 6;
    const int L    = tid & 63;
    const int c    = L & 15;
    const int quad = L >> 4;
    const int row0 = blockIdx.x * 64 + w * 16;
    const int arow = row0 + c;

    f32x4 acc[16];
#pragma unroll
    for (int i = 0; i < 16; i++) acc[i] = (f32x4)0.f;

#define PSTAGE(kc, p)                                                          \
    {                                                                          \
        _Pragma("unroll")                                                      \
        for (int ii = 0; ii < 4; ii++) {                                       \
            int i = w * 4 + ii;                                                \
            gl_lds16(Whf + (size_t)(kc) * 8192 + i * 512 + L * 8,              \
                     (char*)Ws + (p) * 16384 + i * 1024);                      \
        }                                                                      \
    }

    PSTAGE(0, 0);
    float4 nx0 = *(const float4*)(y + (size_t)arow * 256 + quad * 8);
    float4 nx1 = *(const float4*)(y + (size_t)arow * 256 + quad * 8 + 4);

    for (int kc = 0; kc < 8; kc++) {
        __syncthreads();
        if (kc < 7) PSTAGE(kc + 1, (kc + 1) & 1);
        float4 cx0 = nx0, cx1 = nx1;
        if (kc < 7) {
            nx0 = *(const float4*)(y + (size_t)arow * 256 + (kc + 1) * 32 + quad * 8);
            nx1 = *(const float4*)(y + (size_t)arow * 256 + (kc + 1) * 32 + quad * 8 + 4);
        }
        float xs[8] = {cx0.x, cx0.y, cx0.z, cx0.w, cx1.x, cx1.y, cx1.z, cx1.w};
        f16x8 ah;
#pragma unroll
        for (int j = 0; j < 8; j++) ah[j] = (_Float16)xs[j];
        const ushort* buf = Ws + (kc & 1) * 8192;
#pragma unroll
        for (int nt = 0; nt < 16; nt++) {
            f16x8 bh = *(const f16x8*)(buf + nt * 512 + L * 8);
            acc[nt] = __builtin_amdgcn_mfma_f32_16x16x32_f16(ah, bh, acc[nt], 0, 0, 0);
        }
    }

    // epilogue: bias+relu, per-wave LDS transpose C-layout -> B-frag layout
    __syncthreads();                 // all waves done reading Ws
    float* tr = (float*)Ws + w * (16 * 130);
    const int rt_g = row0 >> 4;
#pragma unroll
    for (int half = 0; half < 2; half++) {
#pragma unroll
        for (int nt8 = 0; nt8 < 8; nt8++) {
            int nt = half * 8 + nt8;
            float bv = bias[nt * 16 + c];
#pragma unroll
            for (int r = 0; r < 4; r++)
                tr[(quad * 4 + r) * 130 + nt8 * 16 + c] = fmaxf(acc[nt][r] + bv, 0.f);
        }
#pragma unroll
        for (int ec4 = 0; ec4 < 4; ec4++) {
            int ec = half * 4 + ec4;
            short8 hh;
#pragma unroll
            for (int j = 0; j < 8; j++)
                hh[j] = (short)f2h(tr[c * 130 + ec4 * 32 + quad * 8 + j]);
            size_t blk = (size_t)(rt_g >> 5) * 256 + ec * 32 + (rt_g & 31);
            *(short8*)(Oy + blk * 512 + L * 8) = hh;
        }
    }
}

// ---- K2: fused x-proj + scores + softmax + match. 32 rows/block, 2048 blocks. ----
// LDS (ushort idx): [0,8192) x-frags -> pfrag (in place) -> red; [8192,24576)
// 2x16KB ping-pong (Whf slabs in proj, ypf granules in A) -> alpha (32KB) for C.
// Phase A wave partition: (rs=w&1, oct=w>>1), 16 steps of [kc][q-half].
__global__ __launch_bounds__(256, 4) void k_attn(const float* __restrict__ x,
                                                 const ushort* __restrict__ Whf,
                                                 const float* __restrict__ bias,
                                                 const ushort* __restrict__ ypf,
                                                 const ushort* __restrict__ yf,
                                                 float* __restrict__ out) {
    __shared__ __align__(16) ushort lds[24576];   // 48KB
    const int tid  = threadIdx.x;
    const int w    = tid >> 6;
    const int L    = tid & 63;
    const int c    = L & 15;
    const int quad = L >> 4;

    // XCD-affinity swizzle: XCD x sees only batches 4x..4x+3
    const int bid = blockIdx.x;
    const int jj  = bid >> 3;
    const int b   = (bid & 7) * 4 + (jj >> 6);
    const int mt  = jj & 63;                       // 0..63, 32 rows each
    const int m0  = mt * 32;

    // ---- stage x A-frags (inline f32->f16) into [0,8192); DMA Whf slab 0 ----
#pragma unroll
    for (int ii = 0; ii < 4; ii++) {
        int unit = w * 4 + ii;
        int rs = unit >> 3, kc = unit & 7;
        const float* xs = x + ((size_t)(b * LP_ + m0 + rs * 16 + c)) * 256 + kc * 32 + quad * 8;
        float4 v0 = *(const float4*)xs;
        float4 v1 = *(const float4*)(xs + 4);
        f16x8 h;
        h[0] = (_Float16)v0.x; h[1] = (_Float16)v0.y;
        h[2] = (_Float16)v0.z; h[3] = (_Float16)v0.w;
        h[4] = (_Float16)v1.x; h[5] = (_Float16)v1.y;
        h[6] = (_Float16)v1.z; h[7] = (_Float16)v1.w;
        *(f16x8*)(lds + unit * 512 + L * 8) = h;
    }
#pragma unroll
    for (int ii = 0; ii < 4; ii++)       // Whf slab 0 -> pingpong buf 0
        gl_lds16(Whf + (size_t)(w * 4 + ii) * 512 + L * 8,
                 (char*)lds + 16384 + (w * 4 + ii) * 1024);

    // ---- x-proj: wave w = e-quarter (4 nt), both row-tiles; Whf from LDS ----
    {
        float bv[4];
#pragma unroll
        for (int ne = 0; ne < 4; ne++) bv[ne] = bias[(w * 4 + ne) * 16 + c];
        f32x4 pacc[2][4];
#pragma unroll
        for (int rs = 0; rs < 2; rs++)
#pragma unroll
            for (int ne = 0; ne < 4; ne++) pacc[rs][ne] = (f32x4)0.f;
#pragma unroll
        for (int kc = 0; kc < 8; kc++) {
            __syncthreads();             // drains prev DMA; x writes (kc==0)
            if (kc < 7) {
#pragma unroll
                for (int ii = 0; ii < 4; ii++)
                    gl_lds16(Whf + (size_t)((kc + 1) * 16 + w * 4 + ii) * 512 + L * 8,
                             (char*)lds + 16384 + ((kc + 1) & 1) * 16384 + (w * 4 + ii) * 1024);
            }
            f16x8 ah0 = *(const f16x8*)(lds + kc * 512 + L * 8);
            f16x8 ah1 = *(const f16x8*)(lds + (8 + kc) * 512 + L * 8);
            const ushort* wbuf = lds + 8192 + (kc & 1) * 8192;
#pragma unroll
            for (int ne = 0; ne < 4; ne++) {
                f16x8 wb = *(const f16x8*)(wbuf + (w * 4 + ne) * 512 + L * 8);
                pacc[0][ne] = __builtin_amdgcn_mfma_f32_16x16x32_f16(ah0, wb, pacc[0][ne], 0, 0, 0);
                pacc[1][ne] = __builtin_amdgcn_mfma_f32_16x16x32_f16(ah1, wb, pacc[1][ne], 0, 0, 0);
            }
        }
        __syncthreads();                 // all proj reads of x/Whf done
        // issue Phase-A stage 0 (kc=0, qH=0) into buf 0
#pragma unroll
        for (int ii = 0; ii < 4; ii++)
            gl_lds16(ypf + ((size_t)b * 256 + (w * 4 + ii)) * 512 + L * 8,
                     (char*)lds + 16384 + (w * 4 + ii) * 1024);
        // scatter relu(acc+bias) f16 -> pfrag [0,8192) in A-frag layout (x dead)
#pragma unroll
        for (int rs = 0; rs < 2; rs++)
#pragma unroll
            for (int ne = 0; ne < 4; ne++) {
#pragma unroll
                for (int r = 0; r < 4; r++) {
                    float v = fmaxf(pacc[rs][ne][r] + bv[ne], 0.f);
                    int off = (rs * 8 + w * 2 + (ne >> 1)) * 512 +
                              ((ne & 1) * 2 + (c >> 3)) * 128 + (quad * 4 + r) * 8 + (c & 7);
                    lds[off] = f2h(v);
                }
            }
    }
    __syncthreads();                     // pfrag visible; stage-0 drained

    // ---- Phase A: 16 DMA-staged steps [kc=s>>1][qH=s&1]; wave=(rsw, ow) ----
    const int rsw = w & 1, ow = w >> 1;
    f32x4 sc2[2][8];
#pragma unroll
    for (int qH = 0; qH < 2; qH++)
#pragma unroll
        for (int t = 0; t < 8; t++) sc2[qH][t] = (f32x4)0.f;
#pragma unroll
    for (int s = 0; s < 16; s++) {
        if (s > 0) __syncthreads();      // drains DMA(s); publishes buf[s&1]
        if (s < 15) {
            int kcn = (s + 1) >> 1, qHn = (s + 1) & 1;
#pragma unroll
            for (int ii = 0; ii < 4; ii++)
                gl_lds16(ypf + ((size_t)b * 256 + kcn * 32 + qHn * 16 + w * 4 + ii) * 512 + L * 8,
                         (char*)lds + 16384 + ((s + 1) & 1) * 16384 + (w * 4 + ii) * 1024);
        }
        int kc = s >> 1, qH = s & 1;
        f16x8 ah = *(const f16x8*)(lds + (rsw * 8 + kc) * 512 + L * 8);
        const ushort* bbuf = lds + 8192 + (s & 1) * 8192;
#pragma unroll
        for (int t = 0; t < 8; t++) {
            f16x8 bh = *(const f16x8*)(bbuf + (ow * 8 + t) * 512 + L * 8);
            sc2[qH][t] = __builtin_amdgcn_mfma_f32_16x16x32_f16(ah, bh, sc2[qH][t], 0, 0, 0);
        }
    }
    __syncthreads();                     // A reads done; [0,8192) reusable

    // ---- Phase B: softmax. Wave holds rows rsw*16..+15, qt={qH*16+ow*8+t}. ----
    float* red  = (float*)lds;           // [32][2] partial max
    float* red2 = red + 64;              // [32][2] partial sum
    float inv[4];
#pragma unroll
    for (int r = 0; r < 4; r++) {
        float pm = sc2[0][0][r];
#pragma unroll
        for (int qH = 0; qH < 2; qH++)
#pragma unroll
            for (int t = 0; t < 8; t++) pm = fmaxf(pm, sc2[qH][t][r]);
#pragma unroll
        for (int mask = 1; mask <= 8; mask <<= 1) pm = fmaxf(pm, __shfl_xor(pm, mask));
        if (c == 0) red[(rsw * 16 + quad * 4 + r) * 2 + ow] = pm;
    }
    __syncthreads();
#pragma unroll
    for (int r = 0; r < 4; r++) {
        int row = rsw * 16 + quad * 4 + r;
        float m = fmaxf(red[row * 2], red[row * 2 + 1]);
        float ps = 0.f;
#pragma unroll
        for (int qH = 0; qH < 2; qH++)
#pragma unroll
            for (int t = 0; t < 8; t++) {
                float e = __expf(sc2[qH][t][r] - m);
                sc2[qH][t][r] = e;
                ps += e;
            }
#pragma unroll
        for (int mask = 1; mask <= 8; mask <<= 1) ps += __shfl_xor(ps, mask);
        if (c == 0) red2[row * 2 + ow] = ps;
    }
    __syncthreads();
#pragma unroll
    for (int r = 0; r < 4; r++) {
        int row = rsw * 16 + quad * 4 + r;
        inv[r] = 1.f / (red2[row * 2] + red2[row * 2 + 1]);
    }
    __syncthreads();                     // red reads done before alpha overwrites dbuf

    // alpha (f16) -> LDS [8192,24576): [32 rows][512 q], xor-swizzled 8-elem chunks
#pragma unroll
    for (int r = 0; r < 4; r++) {
        int m_loc = rsw * 16 + quad * 4 + r;
        int swz = m_loc & 7;
        float iv = inv[r];
#pragma unroll
        for (int qH = 0; qH < 2; qH++)
#pragma unroll
            for (int t = 0; t < 8; t++) {
                int q = (qH * 16 + ow * 8 + t) * 16 + c;
                lds[8192 + m_loc * 512 + (((q >> 3) ^ swz) << 3) + (c & 7)] =
                    f2h(sc2[qH][t][r] * iv);
            }
    }
    __syncthreads();

    // ---- Phase C: out = alpha(LDS) @ yf(global). wave w = d-quarter, full q sweep. ----
    f32x4 o[2][4];
#pragma unroll
    for (int rs = 0; rs < 2; rs++)
#pragma unroll
        for (int dt = 0; dt < 4; dt++) o[rs][dt] = (f32x4)0.f;
    const int dh = w;
    const int swzA = c & 7;              // (rs*16+c)&7 == c&7
    for (int kcq = 0; kcq < 16; kcq++) {
        int chunk = kcq * 4 + quad;
        f16x8 af0 = *(const f16x8*)(lds + 8192 + c * 512 + ((chunk ^ swzA) << 3));
        f16x8 af1 = *(const f16x8*)(lds + 8192 + (16 + c) * 512 + ((chunk ^ swzA) << 3));
        const ushort* ybf = yf + ((size_t)(b * 256 + kcq * 16 + dh * 4)) * 512;
#pragma unroll
        for (int dt = 0; dt < 4; dt++) {
            f16x8 bfr = *(const f16x8*)(ybf + dt * 512 + L * 8);
            o[0][dt] = __builtin_amdgcn_mfma_f32_16x16x32_f16(af0, bfr, o[0][dt], 0, 0, 0);
            o[1][dt] = __builtin_amdgcn_mfma_f32_16x16x32_f16(af1, bfr, o[1][dt], 0, 0, 0);
        }
    }

    // ---- direct store (each wave owns a d-quarter, full q summed) ----
#pragma unroll
    for (int rs = 0; rs < 2; rs++)
#pragma unroll
        for (int dt = 0; dt < 4; dt++)
#pragma unroll
            for (int r = 0; r < 4; r++) {
                int row = rs * 16 + quad * 4 + r;
                out[(size_t)(b * LP_ + m0 + row) * 256 + dh * 64 + dt * 16 + c] =
                    o[rs][dt][r];
            }
}

extern "C" void kernel_launch(void* const* d_in, const int* in_sizes, int n_in,
                              void* d_out, int out_size, void* d_ws, size_t ws_size,
                              hipStream_t stream) {
    const float* x    = (const float*)d_in[0];
    const float* y    = (const float*)d_in[1];
    const float* W    = (const float*)d_in[2];
    const float* bias = (const float*)d_in[3];
    float* out = (float*)d_out;

    char* ws = (char*)d_ws;
    size_t off = 0;
    ushort* Whf = (ushort*)(ws + off); off += (size_t)D_ * D_ * 2;          // 128KB
    ushort* yfb = (ushort*)(ws + off); off += (size_t)B_ * D_ * LQ_ * 2;    // 8MB
    ushort* ypf = (ushort*)(ws + off); off += (size_t)B_ * LQ_ * D_ * 2;    // 8MB

    k_prep<<<768, 256, 0, stream>>>(W, y, Whf, yfb);
    k_proj<<<256, 256, 0, stream>>>(y, Whf, bias, ypf);
    k_attn<<<B_ * 64, 256, 0, stream>>>(x, Whf, bias, ypf, yfb, out);
}

// Round 10
// 204.345 us; speedup vs baseline: 1.0107x; 1.0101x over previous
//
#include <hip/hip_runtime.h>
#include <stdint.h>

// SeqAttnMatch: B=32, LP=2048, LQ=512, D=256, fp32 in/out. Single-plane fp16 pipeline.
// k_attn: fused x-proj + scores + softmax + match. Phases A/C use wave-private
// 2-deep DMA double-buffers with counted vmcnt (no barriers, never vmcnt(0) mid-loop).
#define B_  32
#define LP_ 2048
#define LQ_ 512
#define D_  256

typedef __attribute__((ext_vector_type(8))) short short8;      // 8 x 16-bit
typedef __attribute__((ext_vector_type(8))) _Float16 f16x8;    // MFMA A/B frag (4 VGPRs)
typedef __attribute__((ext_vector_type(4))) float f32x4;

__device__ __forceinline__ ushort f2h(float x) {
    union { _Float16 h; ushort u; } v;
    v.h = (_Float16)x;                 // RNE convert
    return v.u;
}
// async global->LDS, 16B/lane; HW writes lds_base + lane*16 (wave-uniform base).
__device__ __forceinline__ void gl_lds16(const void* g, void* l) {
    __builtin_amdgcn_global_load_lds(
        (const __attribute__((address_space(1))) void*)g,
        (__attribute__((address_space(3))) void*)l, 16, 0, 0);
}

// Fragment-blocked layout: 1KB blocks of 512 ushorts. Element for lane
// L=quad*16+c, position L*8 + j, holds M[row_tile*16 + c][k0 + quad*8 + j].

// ---- K0: fused W f32->f16 frag convert (blocks 0..255) + y transpose (256..767) ----
__global__ void k_prep(const float* __restrict__ W, const float* __restrict__ y,
                       ushort* __restrict__ Whf, ushort* __restrict__ yf) {
    __shared__ float t[32 * 260];
    if (blockIdx.x < 256) {
        int i = blockIdx.x * 256 + threadIdx.x;
        int e = i >> 8, k = i & 255;
        size_t off = (size_t)((k >> 5) * 16 + (e >> 4)) * 512 +
                     ((k >> 3) & 3) * 128 + (e & 15) * 8 + (k & 7);
        Whf[off] = f2h(W[i]);
        return;
    }
    int bid = blockIdx.x - 256;      // 512 blocks
    int b = bid >> 4, qc = bid & 15;
    int tid = threadIdx.x;
    int ql = tid >> 3;               // 0..31
    int d0 = (tid & 7) * 4;
#pragma unroll
    for (int p = 0; p < 8; p++) {
        int d = p * 32 + d0;
        float4 v = *(const float4*)(y + ((size_t)(b * LQ_ + qc * 32 + ql) * 256 + d));
        t[ql * 260 + d + 0] = v.x; t[ql * 260 + d + 1] = v.y;
        t[ql * 260 + d + 2] = v.z; t[ql * 260 + d + 3] = v.w;
    }
    __syncthreads();
    int w = tid >> 6, L = tid & 63, c = L & 15, quad = L >> 4;
#pragma unroll
    for (int ii = 0; ii < 4; ii++) {
        int nt = w * 4 + ii;
        short8 o;
#pragma unroll
        for (int j = 0; j < 8; j++)
            o[j] = (short)f2h(t[(quad * 8 + j) * 260 + nt * 16 + c]);
        *(short8*)(yf + ((size_t)(b * 256 + qc * 16 + nt) * 512 + L * 8)) = o;
    }
}

// ---- K1: y-proj = relu(y @ W^T + b) -> frag-blocked f16 (256 blocks, 64 rows each) ----
__global__ __launch_bounds__(256, 3) void k_proj(const float* __restrict__ y,
                                                 const ushort* __restrict__ Whf,
                                                 const float* __restrict__ bias,
                                                 ushort* __restrict__ Oy) {
    __shared__ __align__(16) ushort Ws[16704];   // 32KB ping-pong, then 33.3KB transpose
    const int tid  = threadIdx.x;
    const int w    = tid >> 6;
    const int L    = tid & 63;
    const int c    = L & 15;
    const int quad = L >> 4;
    const int row0 = blockIdx.x * 64 + w * 16;
    const int arow = row0 + c;

    f32x4 acc[16];
#pragma unroll
    for (int i = 0; i < 16; i++) acc[i] = (f32x4)0.f;

#define PSTAGE(kc, p)                                                          \
    {                                                                          \
        _Pragma("unroll")                                                      \
        for (int ii = 0; ii < 4; ii++) {                                       \
            int i = w * 4 + ii;                                                \
            gl_lds16(Whf + (size_t)(kc) * 8192 + i * 512 + L * 8,              \
                     (char*)Ws + (p) * 16384 + i * 1024);                      \
        }                                                                      \
    }

    PSTAGE(0, 0);
    float4 nx0 = *(const float4*)(y + (size_t)arow * 256 + quad * 8);
    float4 nx1 = *(const float4*)(y + (size_t)arow * 256 + quad * 8 + 4);

    for (int kc = 0; kc < 8; kc++) {
        __syncthreads();
        if (kc < 7) PSTAGE(kc + 1, (kc + 1) & 1);
        float4 cx0 = nx0, cx1 = nx1;
        if (kc < 7) {
            nx0 = *(const float4*)(y + (size_t)arow * 256 + (kc + 1) * 32 + quad * 8);
            nx1 = *(const float4*)(y + (size_t)arow * 256 + (kc + 1) * 32 + quad * 8 + 4);
        }
        float xs[8] = {cx0.x, cx0.y, cx0.z, cx0.w, cx1.x, cx1.y, cx1.z, cx1.w};
        f16x8 ah;
#pragma unroll
        for (int j = 0; j < 8; j++) ah[j] = (_Float16)xs[j];
        const ushort* buf = Ws + (kc & 1) * 8192;
#pragma unroll
        for (int nt = 0; nt < 16; nt++) {
            f16x8 bh = *(const f16x8*)(buf + nt * 512 + L * 8);
            acc[nt] = __builtin_amdgcn_mfma_f32_16x16x32_f16(ah, bh, acc[nt], 0, 0, 0);
        }
    }

    // epilogue: bias+relu, per-wave LDS transpose C-layout -> B-frag layout
    __syncthreads();                 // all waves done reading Ws
    float* tr = (float*)Ws + w * (16 * 130);
    const int rt_g = row0 >> 4;
#pragma unroll
    for (int half = 0; half < 2; half++) {
#pragma unroll
        for (int nt8 = 0; nt8 < 8; nt8++) {
            int nt = half * 8 + nt8;
            float bv = bias[nt * 16 + c];
#pragma unroll
            for (int r = 0; r < 4; r++)
                tr[(quad * 4 + r) * 130 + nt8 * 16 + c] = fmaxf(acc[nt][r] + bv, 0.f);
        }
#pragma unroll
        for (int ec4 = 0; ec4 < 4; ec4++) {
            int ec = half * 4 + ec4;
            short8 hh;
#pragma unroll
            for (int j = 0; j < 8; j++)
                hh[j] = (short)f2h(tr[c * 130 + ec4 * 32 + quad * 8 + j]);
            size_t blk = (size_t)(rt_g >> 5) * 256 + ec * 32 + (rt_g & 31);
            *(short8*)(Oy + blk * 512 + L * 8) = hh;
        }
    }
}

// ---- K2: fused x-proj + scores + softmax + match. 32 rows/block, 2048 blocks. ----
// LDS 48KB (ushort idx): [0,8192) x-frags -> A-stage (waves 0,1) -> alpha lo;
// [8192,16384) pfrag -> alpha hi; [16384,24576) A-stage (waves 2,3) -> C-stage.
__global__ __launch_bounds__(256, 3) void k_attn(const float* __restrict__ x,
                                                 const ushort* __restrict__ Whf,
                                                 const float* __restrict__ bias,
                                                 const ushort* __restrict__ ypf,
                                                 const ushort* __restrict__ yf,
                                                 float* __restrict__ out) {
    __shared__ __align__(16) ushort lds[24576];   // 48KB
    const int tid  = threadIdx.x;
    const int w    = tid >> 6;
    const int L    = tid & 63;
    const int c    = L & 15;
    const int quad = L >> 4;

    // XCD-affinity swizzle: XCD x sees only batches 4x..4x+3
    const int bid = blockIdx.x;
    const int jj  = bid >> 3;
    const int b   = (bid & 7) * 4 + (jj >> 6);
    const int mt  = jj & 63;                       // 0..63, 32 rows each
    const int m0  = mt * 32;

    // ---- stage x A-frags (inline f32->f16): 16 units (rs*8+kc) x 1KB ----
#pragma unroll
    for (int ii = 0; ii < 4; ii++) {
        int unit = w * 4 + ii;
        int rs = unit >> 3, kc = unit & 7;
        const float* xs = x + ((size_t)(b * LP_ + m0 + rs * 16 + c)) * 256 + kc * 32 + quad * 8;
        float4 v0 = *(const float4*)xs;
        float4 v1 = *(const float4*)(xs + 4);
        f16x8 h;
        h[0] = (_Float16)v0.x; h[1] = (_Float16)v0.y;
        h[2] = (_Float16)v0.z; h[3] = (_Float16)v0.w;
        h[4] = (_Float16)v1.x; h[5] = (_Float16)v1.y;
        h[6] = (_Float16)v1.z; h[7] = (_Float16)v1.w;
        *(f16x8*)(lds + unit * 512 + L * 8) = h;
    }
    __syncthreads();                 // x-frags visible

    // ---- x-proj: wave w = e-quarter (4 nt), both row-tiles; Whf from L2 ----
    {
        float bv[4];
#pragma unroll
        for (int ne = 0; ne < 4; ne++) bv[ne] = bias[(w * 4 + ne) * 16 + c];
        f32x4 pacc[2][4];
#pragma unroll
        for (int rs = 0; rs < 2; rs++)
#pragma unroll
            for (int ne = 0; ne < 4; ne++) pacc[rs][ne] = (f32x4)0.f;
        for (int kc = 0; kc < 8; kc++) {
            f16x8 ah0 = *(const f16x8*)(lds + kc * 512 + L * 8);
            f16x8 ah1 = *(const f16x8*)(lds + (8 + kc) * 512 + L * 8);
#pragma unroll
            for (int ne = 0; ne < 4; ne++) {
                f16x8 wb = *(const f16x8*)(Whf + ((size_t)(kc * 16 + w * 4 + ne)) * 512 + L * 8);
                pacc[0][ne] = __builtin_amdgcn_mfma_f32_16x16x32_f16(ah0, wb, pacc[0][ne], 0, 0, 0);
                pacc[1][ne] = __builtin_amdgcn_mfma_f32_16x16x32_f16(ah1, wb, pacc[1][ne], 0, 0, 0);
            }
        }
        // scatter relu(acc+bias) f16 -> pfrag [8192,16384) in A-frag layout.
#pragma unroll
        for (int rs = 0; rs < 2; rs++)
#pragma unroll
            for (int ne = 0; ne < 4; ne++) {
#pragma unroll
                for (int r = 0; r < 4; r++) {
                    float v = fmaxf(pacc[rs][ne][r] + bv[ne], 0.f);
                    int off = 8192 + (rs * 8 + w * 2 + (ne >> 1)) * 512 +
                              ((ne & 1) * 2 + (c >> 3)) * 128 + (quad * 4 + r) * 8 + (c & 7);
                    lds[off] = f2h(v);
                }
            }
    }

    f32x4 sc[2][8];
#pragma unroll
    for (int rs = 0; rs < 2; rs++)
#pragma unroll
        for (int qt = 0; qt < 8; qt++) sc[rs][qt] = (f32x4)0.f;
    __syncthreads();                 // pfrag visible; x region now free for A-stage

    // ---- Phase A: wave-private 2-deep DMA pipeline, BARRIER-FREE. ----
    // Wave w owns q-quarter w. Step s: kc=s>>1, qhalf=s&1, 4KB granule (4 qt frags).
    // Buffers: wave base abase, 2 x 2048 ushorts. vmcnt ledger: prologue 8 out;
    // per step wait vmcnt(4) (oldest granule done), read to regs, lgkmcnt(0),
    // THEN reissue same buffer for s+2. Final step waits vmcnt(0).
    asm volatile("s_waitcnt vmcnt(0)" ::: "memory");   // isolate ledger from proj loads
    const int abase = (w & 1) * 4096 + (w >> 1) * 16384;
#pragma unroll
    for (int i = 0; i < 4; i++)          // stage 0: kc0, qhalf0
        gl_lds16(ypf + ((size_t)b * 256 + w * 8 + i) * 512 + L * 8,
                 (char*)lds + (size_t)(abase + i * 512) * 2);
#pragma unroll
    for (int i = 0; i < 4; i++)          // stage 1: kc0, qhalf1
        gl_lds16(ypf + ((size_t)b * 256 + w * 8 + 4 + i) * 512 + L * 8,
                 (char*)lds + (size_t)(abase + 2048 + i * 512) * 2);
#pragma unroll
    for (int s = 0; s < 16; s++) {
        if (s < 15) { asm volatile("s_waitcnt vmcnt(4)" ::: "memory"); }
        else        { asm volatile("s_waitcnt vmcnt(0)" ::: "memory"); }
        const int kc = s >> 1, qhf = s & 1;
        const ushort* sb = lds + abase + (s & 1) * 2048;
        f16x8 ah0 = *(const f16x8*)(lds + 8192 + kc * 512 + L * 8);
        f16x8 ah1 = *(const f16x8*)(lds + 8192 + (8 + kc) * 512 + L * 8);
        f16x8 bh0 = *(const f16x8*)(sb + 0 * 512 + L * 8);
        f16x8 bh1 = *(const f16x8*)(sb + 1 * 512 + L * 8);
        f16x8 bh2 = *(const f16x8*)(sb + 2 * 512 + L * 8);
        f16x8 bh3 = *(const f16x8*)(sb + 3 * 512 + L * 8);
        asm volatile("s_waitcnt lgkmcnt(0)" ::: "memory");   // regs safe before reissue
        if (s < 14) {
            const int kn = (s + 2) >> 1, qn = (s + 2) & 1;
#pragma unroll
            for (int i = 0; i < 4; i++)
                gl_lds16(ypf + ((size_t)b * 256 + kn * 32 + w * 8 + qn * 4 + i) * 512 + L * 8,
                         (char*)lds + (size_t)(abase + (s & 1) * 2048 + i * 512) * 2);
        }
        sc[0][qhf * 4 + 0] = __builtin_amdgcn_mfma_f32_16x16x32_f16(ah0, bh0, sc[0][qhf * 4 + 0], 0, 0, 0);
        sc[1][qhf * 4 + 0] = __builtin_amdgcn_mfma_f32_16x16x32_f16(ah1, bh0, sc[1][qhf * 4 + 0], 0, 0, 0);
        sc[0][qhf * 4 + 1] = __builtin_amdgcn_mfma_f32_16x16x32_f16(ah0, bh1, sc[0][qhf * 4 + 1], 0, 0, 0);
        sc[1][qhf * 4 + 1] = __builtin_amdgcn_mfma_f32_16x16x32_f16(ah1, bh1, sc[1][qhf * 4 + 1], 0, 0, 0);
        sc[0][qhf * 4 + 2] = __builtin_amdgcn_mfma_f32_16x16x32_f16(ah0, bh2, sc[0][qhf * 4 + 2], 0, 0, 0);
        sc[1][qhf * 4 + 2] = __builtin_amdgcn_mfma_f32_16x16x32_f16(ah1, bh2, sc[1][qhf * 4 + 2], 0, 0, 0);
        sc[0][qhf * 4 + 3] = __builtin_amdgcn_mfma_f32_16x16x32_f16(ah0, bh3, sc[0][qhf * 4 + 3], 0, 0, 0);
        sc[1][qhf * 4 + 3] = __builtin_amdgcn_mfma_f32_16x16x32_f16(ah1, bh3, sc[1][qhf * 4 + 3], 0, 0, 0);
    }

    // ---- Phase B: softmax; each wave holds a q-quarter of every row ----
    __syncthreads();                 // all waves done Phase A; stage regions dead
    float* red  = (float*)lds;       // [32][4] partial max
    float* red2 = red + 128;         // [32][4] partial sum
    float inv[2][4];
#pragma unroll
    for (int rs = 0; rs < 2; rs++)
#pragma unroll
        for (int r = 0; r < 4; r++) {
            float pm = sc[rs][0][r];
#pragma unroll
            for (int qt = 1; qt < 8; qt++) pm = fmaxf(pm, sc[rs][qt][r]);
#pragma unroll
            for (int mask = 1; mask <= 8; mask <<= 1) pm = fmaxf(pm, __shfl_xor(pm, mask));
            if (c == 0) red[(rs * 16 + quad * 4 + r) * 4 + w] = pm;
        }
    __syncthreads();
#pragma unroll
    for (int rs = 0; rs < 2; rs++)
#pragma unroll
        for (int r = 0; r < 4; r++) {
            int row = rs * 16 + quad * 4 + r;
            float m = fmaxf(fmaxf(red[row * 4], red[row * 4 + 1]),
                            fmaxf(red[row * 4 + 2], red[row * 4 + 3]));
            float ps = 0.f;
#pragma unroll
            for (int qt = 0; qt < 8; qt++) {
                float e = __expf(sc[rs][qt][r] - m);
                sc[rs][qt][r] = e;
                ps += e;
            }
#pragma unroll
            for (int mask = 1; mask <= 8; mask <<= 1) ps += __shfl_xor(ps, mask);
            if (c == 0) red2[row * 4 + w] = ps;
        }
    __syncthreads();
#pragma unroll
    for (int rs = 0; rs < 2; rs++)
#pragma unroll
        for (int r = 0; r < 4; r++) {
            int row = rs * 16 + quad * 4 + r;
            inv[rs][r] = 1.f / (red2[row * 4] + red2[row * 4 + 1] +
                                red2[row * 4 + 2] + red2[row * 4 + 3]);
        }
    __syncthreads();                 // red reads done before alpha overwrites

    // alpha (f16) -> LDS [0,16384): [32 rows][512 q], xor-swizzled 8-elem chunks
#pragma unroll
    for (int rs = 0; rs < 2; rs++)
#pragma unroll
        for (int r = 0; r < 4; r++) {
            int m_loc = rs * 16 + quad * 4 + r;
            int swz = m_loc & 7;
            float iv = inv[rs][r];
#pragma unroll
            for (int qt = 0; qt < 8; qt++) {
                int q = w * 128 + qt * 16 + c;
                lds[m_loc * 512 + (((q >> 3) ^ swz) << 3) + (c & 7)] = f2h(sc[rs][qt][r] * iv);
            }
        }
    __syncthreads();                 // alpha visible; [16384,24576) free for C-stage

    // ---- Phase C: wave-private 2-deep DMA pipeline, BARRIER-FREE. ----
    // Wave w = d-quarter. Step s: kcq=s>>1, dpair=s&1, 2KB granule (2 dt frags).
    f32x4 o[2][4];
#pragma unroll
    for (int rs = 0; rs < 2; rs++)
#pragma unroll
        for (int dt = 0; dt < 4; dt++) o[rs][dt] = (f32x4)0.f;
    const int swzA = c & 7;          // (rs*16+c)&7 == c&7
    asm volatile("s_waitcnt vmcnt(0)" ::: "memory");
    const int cbase = 16384 + w * 2048;
#pragma unroll
    for (int i = 0; i < 2; i++)          // stage 0: kcq0, dpair0
        gl_lds16(yf + ((size_t)(b * 256 + w * 4 + i)) * 512 + L * 8,
                 (char*)lds + (size_t)(cbase + i * 512) * 2);
#pragma unroll
    for (int i = 0; i < 2; i++)          // stage 1: kcq0, dpair1
        gl_lds16(yf + ((size_t)(b * 256 + w * 4 + 2 + i)) * 512 + L * 8,
                 (char*)lds + (size_t)(cbase + 1024 + i * 512) * 2);
#pragma unroll
    for (int s = 0; s < 32; s++) {
        if (s < 31) { asm volatile("s_waitcnt vmcnt(2)" ::: "memory"); }
        else        { asm volatile("s_waitcnt vmcnt(0)" ::: "memory"); }
        const int kcq = s >> 1, dp = s & 1;
        const ushort* sb = lds + cbase + (s & 1) * 1024;
        const int chunk = kcq * 4 + quad;
        f16x8 af0 = *(const f16x8*)(lds + c * 512 + ((chunk ^ swzA) << 3));
        f16x8 af1 = *(const f16x8*)(lds + (16 + c) * 512 + ((chunk ^ swzA) << 3));
        f16x8 bf0 = *(const f16x8*)(sb + L * 8);
        f16x8 bf1 = *(const f16x8*)(sb + 512 + L * 8);
        asm volatile("s_waitcnt lgkmcnt(0)" ::: "memory");
        if (s < 30) {
            const int kn = (s + 2) >> 1, dn = (s + 2) & 1;
#pragma unroll
            for (int i = 0; i < 2; i++)
                gl_lds16(yf + ((size_t)(b * 256 + kn * 16 + w * 4 + dn * 2 + i)) * 512 + L * 8,
                         (char*)lds + (size_t)(cbase + (s & 1) * 1024 + i * 512) * 2);
        }
        o[0][dp * 2 + 0] = __builtin_amdgcn_mfma_f32_16x16x32_f16(af0, bf0, o[0][dp * 2 + 0], 0, 0, 0);
        o[1][dp * 2 + 0] = __builtin_amdgcn_mfma_f32_16x16x32_f16(af1, bf0, o[1][dp * 2 + 0], 0, 0, 0);
        o[0][dp * 2 + 1] = __builtin_amdgcn_mfma_f32_16x16x32_f16(af0, bf1, o[0][dp * 2 + 1], 0, 0, 0);
        o[1][dp * 2 + 1] = __builtin_amdgcn_mfma_f32_16x16x32_f16(af1, bf1, o[1][dp * 2 + 1], 0, 0, 0);
    }

    // ---- direct store (each wave owns a d-quarter, full q summed) ----
#pragma unroll
    for (int rs = 0; rs < 2; rs++)
#pragma unroll
        for (int dt = 0; dt < 4; dt++)
#pragma unroll
            for (int r = 0; r < 4; r++) {
                int row = rs * 16 + quad * 4 + r;
                out[(size_t)(b * LP_ + m0 + row) * 256 + w * 64 + dt * 16 + c] =
                    o[rs][dt][r];
            }
}

extern "C" void kernel_launch(void* const* d_in, const int* in_sizes, int n_in,
                              void* d_out, int out_size, void* d_ws, size_t ws_size,
                              hipStream_t stream) {
    const float* x    = (const float*)d_in[0];
    const float* y    = (const float*)d_in[1];
    const float* W    = (const float*)d_in[2];
    const float* bias = (const float*)d_in[3];
    float* out = (float*)d_out;

    char* ws = (char*)d_ws;
    size_t off = 0;
    ushort* Whf = (ushort*)(ws + off); off += (size_t)D_ * D_ * 2;          // 128KB
    ushort* yfb = (ushort*)(ws + off); off += (size_t)B_ * D_ * LQ_ * 2;    // 8MB
    ushort* ypf = (ushort*)(ws + off); off += (size_t)B_ * LQ_ * D_ * 2;    // 8MB

    k_prep<<<768, 256, 0, stream>>>(W, y, Whf, yfb);
    k_proj<<<256, 256, 0, stream>>>(y, Whf, bias, ypf);
    k_attn<<<B_ * 64, 256, 0, stream>>>(x, Whf, bias, ypf, yfb, out);
}